// Round 7
// baseline (463.042 us; speedup 1.0000x reference)
//
#include <hip/hip_runtime.h>
#include <hip/hip_bf16.h>

typedef __hip_bfloat16 bf16;
typedef __attribute__((ext_vector_type(8))) short short8;
typedef __attribute__((ext_vector_type(4))) float floatx4;

#define L_SEQ 4096
#define B_SZ 4
#define NROW 16384          // B*L
#define NK 12
#define DIM_CONV 1548
#define Z_LD 1552           // z0 row stride: [0,768)=kv, [768,1536)=q, [1536,1548)=s
#define OUT_CPLX 1536
#define CS_LD 1552          // cs row stride: [0,768)=re, [768,1536)=im, [1536,1548)=pw
#define NCHUNK 128
#define CLEN 32

__device__ __forceinline__ float bf2f(bf16 v) { return __bfloat162float(v); }
__device__ __forceinline__ float s2f(short v) {
    unsigned u = ((unsigned)(unsigned short)v) << 16;
    return __builtin_bit_cast(float, u);
}
__device__ __forceinline__ short f2s(float x) {
    bf16 b = __float2bfloat16(x);
    return __builtin_bit_cast(short, b);
}
__device__ __forceinline__ float frcp(float x) { return __builtin_amdgcn_rcpf(x); }
__device__ __forceinline__ float fsigmoid(float x) { return frcp(1.0f + __expf(-x)); }
__device__ __forceinline__ float fsilu(float x) { return x * fsigmoid(x); }
__device__ __forceinline__ float fsoftplus(float x) {
    return fmaxf(x, 0.0f) + __logf(1.0f + __expf(-fabsf(x)));
}

// ---------------------------------------------------------------------------
// GEMM core v2 (128x128 tile, 64x64 wave tile, BK=64, XOR swizzle).
// 124 regs/wave (60 VGPR + 64 AGPR acc), 32 KB LDS -> up to 4 blocks/CU.
// ---------------------------------------------------------------------------
#define GEMM_CORE2(A_, lda_, Bt_, ldb_, Kd_)                                             \
    __shared__ __align__(16) short lds_a[128 * 64];                                      \
    __shared__ __align__(16) short lds_b[128 * 64];                                      \
    const int tid = threadIdx.x;                                                         \
    const int wave = tid >> 6;                                                           \
    const int lane = tid & 63;                                                           \
    const bf16* ga[4];                                                                   \
    const bf16* gb[4];                                                                   \
    short* la[4];                                                                        \
    short* lb[4];                                                                        \
    _Pragma("unroll") for (int s = 0; s < 4; s++) {                                      \
        int p = s * 256 + tid;                                                           \
        int row = p >> 3;                                                                \
        int k8 = (p & 7) ^ (row & 7);                                                    \
        ga[s] = A_ + (size_t)row * lda_ + k8 * 8;                                        \
        gb[s] = Bt_ + (size_t)row * ldb_ + k8 * 8;                                       \
        la[s] = lds_a + (size_t)(s * 256 + wave * 64) * 8;                               \
        lb[s] = lds_b + (size_t)(s * 256 + wave * 64) * 8;                               \
    }                                                                                    \
    floatx4 acc[4][4];                                                                   \
    _Pragma("unroll") for (int i = 0; i < 4; i++)                                        \
        _Pragma("unroll") for (int j = 0; j < 4; j++)                                    \
            acc[i][j] = (floatx4){0.f, 0.f, 0.f, 0.f};                                   \
    const int wm = (wave >> 1) * 64;                                                     \
    const int wn = (wave & 1) * 64;                                                      \
    const int lrow = lane & 15;                                                          \
    const int lk8 = lane >> 4;                                                           \
    for (int k0 = 0; k0 < Kd_; k0 += 64) {                                               \
        _Pragma("unroll") for (int s = 0; s < 4; s++) {                                  \
            __builtin_amdgcn_global_load_lds((const __attribute__((address_space(1))) void*)ga[s], \
                                             (__attribute__((address_space(3))) void*)la[s], 16, 0, 0); \
            __builtin_amdgcn_global_load_lds((const __attribute__((address_space(1))) void*)gb[s], \
                                             (__attribute__((address_space(3))) void*)lb[s], 16, 0, 0); \
            ga[s] += 64; gb[s] += 64;                                                    \
        }                                                                                \
        __syncthreads();                                                                 \
        _Pragma("unroll") for (int s2 = 0; s2 < 2; s2++) {                               \
            short8 af[4], bfv[4];                                                        \
            const int k8L = s2 * 4 + lk8;                                                \
            _Pragma("unroll") for (int i = 0; i < 4; i++) {                              \
                int m = wm + i * 16 + lrow;                                              \
                af[i] = *(const short8*)(lds_a + ((size_t)m * 8 + (k8L ^ (m & 7))) * 8); \
            }                                                                            \
            _Pragma("unroll") for (int j = 0; j < 4; j++) {                              \
                int n = wn + j * 16 + lrow;                                              \
                bfv[j] = *(const short8*)(lds_b + ((size_t)n * 8 + (k8L ^ (n & 7))) * 8); \
            }                                                                            \
            _Pragma("unroll") for (int i = 0; i < 4; i++)                                \
                _Pragma("unroll") for (int j = 0; j < 4; j++)                            \
                    acc[i][j] = __builtin_amdgcn_mfma_f32_16x16x32_bf16(af[i], bfv[j], acc[i][j], 0, 0, 0); \
        }                                                                                \
        __syncthreads();                                                                 \
    }

// AXSW: A-panel indexed by blockIdx.y, B by blockIdx.x -> the N-tile blocks
// sharing one A-panel are dispatch-consecutive, keeping the panel L2-hot
// (r6: z0 FETCH 52 MB vs 28 MB unique input = cross-dispatch eviction).
template <bool OUT_BF16, bool AXSW>
__global__ __launch_bounds__(256, 4) void gemm_kernel(
    const bf16* __restrict__ A, int lda,
    const bf16* __restrict__ Bt, int ldb,
    void* __restrict__ Cv, int ldc, int Kd, int nmax)
{
    const int mb = AXSW ? blockIdx.y : blockIdx.x;
    const int nb = AXSW ? blockIdx.x : blockIdx.y;
    const bf16* Ab = A + (size_t)mb * 128 * lda;
    const bf16* Bb = Bt + (size_t)nb * 128 * ldb;
    GEMM_CORE2(Ab, lda, Bb, ldb, Kd)
    const int orow = mb * 128 + wm + (lk8 << 2);
    const int ocol = nb * 128 + wn + lrow;
    if (OUT_BF16) {
        bf16* C = (bf16*)Cv;
#pragma unroll
        for (int i = 0; i < 4; i++)
#pragma unroll
            for (int j = 0; j < 4; j++)
                if (ocol + j * 16 < nmax)
#pragma unroll
                    for (int r = 0; r < 4; r++)
                        C[(size_t)(orow + i * 16 + r) * ldc + (ocol + j * 16)] =
                            __float2bfloat16(acc[i][j][r]);
    } else {
        float* C = (float*)Cv;
#pragma unroll
        for (int i = 0; i < 4; i++)
#pragma unroll
            for (int j = 0; j < 4; j++)
                if (ocol + j * 16 < nmax)
#pragma unroll
                    for (int r = 0; r < 4; r++)
                        C[(size_t)(orow + i * 16 + r) * ldc + (ocol + j * 16)] = acc[i][j][r];
    }
}

// ---------------------------------------------------------------------------
// Readout GEMM + fused GLU, v2 (r7): WT_RO uses 16-col-block interleave so a
// thread's acc[i][2p]=val and acc[i][2p+1]=gate are in the SAME lane ->
// GLU with no shuffle and half the sigmoids. Output staged through LDS
// (XOR-swizzled, conflict-free) then written as coalesced short8 — global
// store instructions 32 -> 4 per thread. (r6 profile: MfmaUtil 12%,
// VALUBusy 42% — epilogue-bound at 300 TF.)
// ---------------------------------------------------------------------------
__global__ __launch_bounds__(256, 3) void gemm_readout_glu(
    const bf16* __restrict__ A, int lda, long a_zoff,
    const bf16* __restrict__ Bt, int ldb, long b_zoff,
    bf16* __restrict__ Y, int Kd)
{
    const int z = blockIdx.z;
    const bf16* Ab = A + (long)z * a_zoff + (size_t)blockIdx.x * 128 * lda;
    const bf16* Bb = Bt + (long)z * b_zoff + (size_t)blockIdx.y * 128 * ldb;
    GEMM_CORE2(Ab, lda, Bb, ldb, Kd)
    // GLU into LDS stage (reuse lds_a; K-loop's trailing barrier covers reuse)
    const int colb = wn >> 1;
#pragma unroll
    for (int i = 0; i < 4; i++) {
        const int row0 = wm + i * 16 + (lk8 << 2);
#pragma unroll
        for (int p = 0; p < 2; p++) {
            const int col = colb + p * 16 + lrow;
#pragma unroll
            for (int r = 0; r < 4; r++) {
                const int row = row0 + r;
                float v = acc[i][2 * p][r];
                float g = acc[i][2 * p + 1][r];
                lds_a[row * 64 + (col ^ ((row & 12) << 2))] = f2s(v * fsigmoid(g));
            }
        }
    }
    __syncthreads();
    bf16* Yk = Y + (long)z * 192 + (size_t)blockIdx.x * 128 * 2304 + (size_t)blockIdx.y * 64;
#pragma unroll
    for (int ch = tid; ch < 1024; ch += 256) {
        const int row = ch >> 3;
        const int c8 = (ch & 7) * 8;
        *(short8*)(Yk + (size_t)row * 2304 + c8) =
            *(const short8*)(lds_a + row * 64 + (c8 ^ ((row & 12) << 2)));
    }
}

// ---------------------------------------------------------------------------
// prep_kernel: ONE launch for x->bf16 convert, w_int table, and all 7 weight
// transposes (fp32->bf16, tiled 32x32 via LDS). blockIdx.x range-dispatched.
// gmode: 0 = plain transpose row=c; 1/2 = W_readout 16-col-block interleave
// (val -> (c>>4)*32+(c&15), gate -> +16) matching gemm_readout_glu v2.
// ---------------------------------------------------------------------------
#define PREP_CONV_BLKS 6144
#define PREP_WINT_BLKS 3
#define PREP_T0 (PREP_CONV_BLKS + PREP_WINT_BLKS)   // 6147
#define PREP_TOTAL (PREP_T0 + 4632)                  // 10779

__global__ __launch_bounds__(256) void prep_kernel(
    const float* __restrict__ x, const float* __restrict__ w_int_raw,
    const float* __restrict__ W_in, const float* __restrict__ W_gate,
    const float* __restrict__ W_out, const float* __restrict__ W_readout,
    bf16* __restrict__ xb, float* __restrict__ wtab,
    bf16* __restrict__ WT_IN, bf16* __restrict__ WT_GATE,
    bf16* __restrict__ WT_OUT, bf16* __restrict__ WT_RO)
{
    __shared__ float tle[32][33];
    const int blk = blockIdx.x;
    const int tid = threadIdx.x;

    if (blk < PREP_CONV_BLKS) {
        long gid = ((long)blk * 256 + tid) * 8;
        float4 a = *(const float4*)(x + gid);
        float4 b = *(const float4*)(x + gid + 4);
        short8 o;
        o[0] = f2s(a.x); o[1] = f2s(a.y); o[2] = f2s(a.z); o[3] = f2s(a.w);
        o[4] = f2s(b.x); o[5] = f2s(b.y); o[6] = f2s(b.z); o[7] = f2s(b.w);
        *(short8*)(xb + gid) = o;
        return;
    }
    if (blk < PREP_T0) {
        int i = (blk - PREP_CONV_BLKS) * 256 + tid;
        if (i < 768) {
            float e = __expf(w_int_raw[i]);
            wtab[i] = e * frcp(e + 1e-6f);
        }
        return;
    }
    int t = blk - PREP_T0;
    const float* in; bf16* out;
    int ld_in, ld_out, R, C, gmode, nx;
    if (t < 576) {                       // W_in kv cols -> WT_IN rows 0..767
        in = W_in; out = WT_IN; ld_in = 1548; ld_out = 768;
        R = 768; C = 768; gmode = 0; nx = 24;
    } else if (t < 1152) {               // W_in q cols 780.. -> rows 768..1535
        t -= 576;
        in = W_in + 780; out = WT_IN + 768L * 768; ld_in = 1548; ld_out = 768;
        R = 768; C = 768; gmode = 0; nx = 24;
    } else if (t < 1176) {               // W_in s cols 768..779 -> rows 1536..1547
        t -= 1152;
        in = W_in + 768; out = WT_IN + 1536L * 768; ld_in = 1548; ld_out = 768;
        R = 768; C = 12; gmode = 0; nx = 1;
    } else if (t < 2328) {               // W_gate
        t -= 1176;
        in = W_gate; out = WT_GATE; ld_in = 1536; ld_out = 768;
        R = 768; C = 1536; gmode = 0; nx = 48;
    } else if (t < 4056) {               // W_out
        t -= 2328;
        in = W_out; out = WT_OUT; ld_in = 768; ld_out = 2304;
        R = 2304; C = 768; gmode = 0; nx = 24;
    } else if (t < 4344) {               // W_readout val half (16-blk interleave)
        t -= 4056;
        int k = t / 24; t %= 24;
        in = W_readout + (long)k * 49152; out = WT_RO + (long)k * 49152;
        ld_in = 384; ld_out = 128; R = 128; C = 192; gmode = 1; nx = 6;
    } else {                             // W_readout gate half
        t -= 4344;
        int k = t / 24; t %= 24;
        in = W_readout + (long)k * 49152 + 192; out = WT_RO + (long)k * 49152;
        ld_in = 384; ld_out = 128; R = 128; C = 192; gmode = 2; nx = 6;
    }
    int c0 = (t % nx) * 32, r0 = (t / nx) * 32;
    int tx = tid & 31, ty = tid >> 5;    // 32x8
#pragma unroll
    for (int i = 0; i < 32; i += 8) {
        int r = r0 + ty + i, c = c0 + tx;
        if (r < R && c < C) tle[ty + i][tx] = in[(size_t)r * ld_in + c];
    }
    __syncthreads();
#pragma unroll
    for (int i = 0; i < 32; i += 8) {
        int c = c0 + ty + i, r = r0 + tx;
        if (c < C && r < R) {
            int orow2 = (gmode == 0) ? c
                       : ((c & 15) + ((c >> 4) << 5) + ((gmode == 2) ? 16 : 0));
            out[(size_t)orow2 * ld_out + r] = __float2bfloat16(tle[tx][ty + i]);
        }
    }
}

// ---------------------------------------------------------------------------
// scan_terms (pw fused): one block per rest=(b,chunk).
// ---------------------------------------------------------------------------
__global__ __launch_bounds__(256) void scan_terms(
    const bf16* __restrict__ z0, const float* __restrict__ conv_w,
    const float* __restrict__ theta_raw, const float* __restrict__ pscale,
    const float* __restrict__ decay, const float* __restrict__ sscale,
    const float* __restrict__ sbias,
    bf16* __restrict__ cs, bf16* __restrict__ qbuf, float* __restrict__ sums)
{
    __shared__ float pwl[CLEN][NK];
    const int rest = blockIdx.x;              // b*128 + chunk
    const int chunk = rest & (NCHUNK - 1);
    const int b = rest >> 7;
    const int l0 = chunk * CLEN;
    const int tau = threadIdx.x;
    const bf16* zb = z0 + (size_t)b * L_SEQ * Z_LD;
    bf16* csb = cs + (size_t)b * L_SEQ * CS_LD;
    const size_t bL = (size_t)b * L_SEQ;
    float* srow = sums + (size_t)rest * 1552;

    if (tau < NK) {
        const int k = tau;
        const int zc = 1536 + k;
        const int wc = 768 + k;
        float w0 = conv_w[0 * DIM_CONV + wc], w1 = conv_w[1 * DIM_CONV + wc];
        float w2 = conv_w[2 * DIM_CONV + wc], w3 = conv_w[3 * DIM_CONV + wc];
        float ss = sscale[k], sb = sbias[k];
        float slope = fsoftplus(decay[k]);
        float h1 = (l0 >= 3) ? bf2f(zb[(size_t)(l0 - 3) * Z_LD + zc]) : 0.f;
        float h2 = (l0 >= 2) ? bf2f(zb[(size_t)(l0 - 2) * Z_LD + zc]) : 0.f;
        float h3 = (l0 >= 1) ? bf2f(zb[(size_t)(l0 - 1) * Z_LD + zc]) : 0.f;
        for (int i = 0; i < CLEN; i++) {
            int l = l0 + i;
            float cur = bf2f(zb[(size_t)l * Z_LD + zc]);
            float s = fsilu(w0 * h1 + w1 * h2 + w2 * h3 + w3 * cur);
            h1 = h2; h2 = h3; h3 = cur;
            float pw = fsoftplus(ss * s + sb) * __expf(-slope * (float)(L_SEQ - 1 - l));
            pwl[i][k] = fminf(fmaxf(pw, 1e-4f), 5000.0f);
        }
    }
    __syncthreads();
    if (tau >= 194) return;

    if (tau < 96) {
        const int cv0 = tau * 8;
        const int k = cv0 >> 6;
        float wt[4][8], th[8];
#pragma unroll
        for (int t = 0; t < 4; t++)
#pragma unroll
            for (int j = 0; j < 8; j++) wt[t][j] = conv_w[t * DIM_CONV + cv0 + j];
#pragma unroll
        for (int j = 0; j < 8; j++)
            th[j] = 0.001f + 2.999f * fsigmoid(theta_raw[cv0 + j]);
        const float ps = pscale[k];
        float h1[8], h2[8], h3[8];
#pragma unroll
        for (int j = 0; j < 8; j++) { h1[j] = 0.f; h2[j] = 0.f; h3[j] = 0.f; }
        if (l0 >= 1) {
            short8 v = *(const short8*)(zb + (size_t)(l0 - 1) * Z_LD + cv0);
#pragma unroll
            for (int j = 0; j < 8; j++) h3[j] = s2f(v[j]);
            short8 u = *(const short8*)(zb + (size_t)(l0 - 2) * Z_LD + cv0);
#pragma unroll
            for (int j = 0; j < 8; j++) h2[j] = s2f(u[j]);
            short8 w = *(const short8*)(zb + (size_t)(l0 - 3) * Z_LD + cv0);
#pragma unroll
            for (int j = 0; j < 8; j++) h1[j] = s2f(w[j]);
        }
        float sre[8], sim[8];
#pragma unroll
        for (int j = 0; j < 8; j++) { sre[j] = 0.f; sim[j] = 0.f; }
        for (int i = 0; i < CLEN; i++) {
            int l = l0 + i;
            short8 zv = *(const short8*)(zb + (size_t)l * Z_LD + cv0);
            float pw = pwl[i][k];
            short8 vr, vi;
#pragma unroll
            for (int j = 0; j < 8; j++) {
                float cur = s2f(zv[j]);
                float kv = fsilu(wt[0][j] * h1[j] + wt[1][j] * h2[j] + wt[2][j] * h3[j] + wt[3][j] * cur);
                h1[j] = h2[j]; h2[j] = h3[j]; h3[j] = cur;
                float ksv = kv * ps;
                float phi = ksv * frcp(1.0f + fabsf(ksv)) * th[j];
                float sn = __sinf(phi);
                float cn = __cosf(phi);
                float kvw = kv * pw;
                short tr = f2s(kvw * cn);
                short ti = f2s(kvw * sn);
                vr[j] = tr; vi[j] = ti;
                sre[j] += s2f(tr);
                sim[j] += s2f(ti);
            }
            *(short8*)(csb + (size_t)l * CS_LD + cv0) = vr;
            *(short8*)(csb + (size_t)l * CS_LD + 768 + cv0) = vi;
        }
#pragma unroll
        for (int j = 0; j < 8; j++) {
            srow[cv0 + j] = sre[j];
            srow[768 + cv0 + j] = sim[j];
        }
    } else if (tau < 192) {
        const int qc0 = (tau - 96) * 8;
        const int zc0 = 768 + qc0;
        const int wc0 = 780 + qc0;
        float wt[4][8];
#pragma unroll
        for (int t = 0; t < 4; t++)
#pragma unroll
            for (int j = 0; j < 8; j++) wt[t][j] = conv_w[t * DIM_CONV + wc0 + j];
        float h1[8], h2[8], h3[8];
#pragma unroll
        for (int j = 0; j < 8; j++) { h1[j] = 0.f; h2[j] = 0.f; h3[j] = 0.f; }
        if (l0 >= 1) {
            short8 v = *(const short8*)(zb + (size_t)(l0 - 1) * Z_LD + zc0);
#pragma unroll
            for (int j = 0; j < 8; j++) h3[j] = s2f(v[j]);
            short8 u = *(const short8*)(zb + (size_t)(l0 - 2) * Z_LD + zc0);
#pragma unroll
            for (int j = 0; j < 8; j++) h2[j] = s2f(u[j]);
            short8 w = *(const short8*)(zb + (size_t)(l0 - 3) * Z_LD + zc0);
#pragma unroll
            for (int j = 0; j < 8; j++) h1[j] = s2f(w[j]);
        }
        for (int i = 0; i < CLEN; i++) {
            int l = l0 + i;
            short8 zv = *(const short8*)(zb + (size_t)l * Z_LD + zc0);
            short8 o;
#pragma unroll
            for (int j = 0; j < 8; j++) {
                float cur = s2f(zv[j]);
                float q = fsilu(wt[0][j] * h1[j] + wt[1][j] * h2[j] + wt[2][j] * h3[j] + wt[3][j] * cur);
                h1[j] = h2[j]; h2[j] = h3[j]; h3[j] = cur;
                o[j] = f2s(q);
            }
            *(short8*)(qbuf + (bL + l) * 768 + qc0) = o;
        }
    } else {
        const int k0 = (tau == 192) ? 0 : 8;
        const int nv = (tau == 192) ? 8 : 4;
        float spw[8];
#pragma unroll
        for (int j = 0; j < 8; j++) spw[j] = 0.f;
        for (int i = 0; i < CLEN; i++) {
            int l = l0 + i;
            short8 o;
#pragma unroll
            for (int j = 0; j < 8; j++) {
                float v = (j < nv) ? pwl[i][k0 + j] : 0.0f;
                short t = f2s(v);
                o[j] = t;
                spw[j] += s2f(t);
            }
            *(short8*)(csb + (size_t)l * CS_LD + 1536 + k0) = o;
        }
#pragma unroll
        for (int j = 0; j < 8; j++) srow[1536 + k0 + j] = spw[j];
    }
}

// ---------------------------------------------------------------------------
// scan_mid v2: parallel LDS-tiled exclusive scan over NCHUNK chunks.
// ---------------------------------------------------------------------------
#define SMID_COLS 64
__global__ __launch_bounds__(256) void scan_mid(float* __restrict__ sums)
{
    __shared__ float tle[NCHUNK][SMID_COLS];   // 32 KB
    const int b = blockIdx.y;
    const int c0 = blockIdx.x * SMID_COLS;
    const int tc = threadIdx.x & 63;
    const int tr = threadIdx.x >> 6;           // 0..3
    const int c = c0 + tc;
    const bool valid = (c < 1552);
    if (valid) {
#pragma unroll
        for (int i = tr; i < NCHUNK; i += 4)
            tle[i][tc] = sums[((size_t)(b * NCHUNK + i)) * 1552 + c];
    }
    __syncthreads();
    if (threadIdx.x < 64 && valid) {
        float run = 0.f;
        for (int i = 0; i < NCHUNK; i++) {
            float v = tle[i][tc];
            tle[i][tc] = run;
            run += v;
        }
    }
    __syncthreads();
    if (valid) {
#pragma unroll
        for (int i = tr; i < NCHUNK; i += 4)
            sums[((size_t)(b * NCHUNK + i)) * 1552 + c] = tle[i][tc];
    }
}

// in-place cumsum over bf16 terms, 8 cols/thread, 16B loads/stores
__global__ __launch_bounds__(256) void scan_inplace(
    bf16* __restrict__ cs, const float* __restrict__ sums)
{
    const int rest = blockIdx.x;
    const int chunk = rest & (NCHUNK - 1);
    const int b = rest >> 7;
    const int tau = threadIdx.x;
    if (tau >= 194) return;
    const int c0 = tau * 8;
    float run[8];
    const float* srow = sums + (size_t)rest * 1552;
#pragma unroll
    for (int j = 0; j < 8; j++) run[j] = srow[c0 + j];
    bf16* p = cs + ((size_t)(b * L_SEQ + chunk * CLEN)) * CS_LD + c0;
    for (int i = 0; i < CLEN; i++) {
        short8 v = *(const short8*)p;
        short8 o;
#pragma unroll
        for (int j = 0; j < 8; j++) {
            run[j] += s2f(v[j]);
            o[j] = f2s(run[j]);
        }
        *(short8*)p = o;
        p += CS_LD;
    }
}

// ---------------------------------------------------------------------------
// match + gated RMSNorm, vectorized: block=192 threads, 8 cols/thread.
// ---------------------------------------------------------------------------
__global__ __launch_bounds__(192) void match_norm_kernel(
    bf16* __restrict__ cs, const bf16* __restrict__ qbuf,
    const bf16* __restrict__ gate, const float* __restrict__ wtab,
    const float* __restrict__ gnw)
{
    const int bl = blockIdx.x;
    bf16* csr = cs + (size_t)bl * CS_LD;
    const bf16* qr = qbuf + (size_t)bl * 768;
    const bf16* gr = gate + (size_t)bl * OUT_CPLX;
    __shared__ float inv_den[NK];
    __shared__ float wsum[3];

    if (threadIdx.x < NK)
        inv_den[threadIdx.x] = 1.0f / fmaxf(bf2f(csr[1536 + threadIdx.x]), 1e-4f);
    __syncthreads();

    const int c0 = threadIdx.x * 8;
    const int k = c0 >> 7;
    const int r0 = c0 & 127;
    const int h0 = r0 & 63;
    const bool is_im = (r0 >= 64);
    const int kq = k >> 1;
    const float idn = inv_den[k];

    short8 re8 = *(const short8*)(csr + k * 64 + h0);
    short8 im8 = *(const short8*)(csr + 768 + k * 64 + h0);
    short8 qa = *(const short8*)(qr + kq * 128 + 2 * h0);
    short8 qb = *(const short8*)(qr + kq * 128 + 2 * h0 + 8);
    short8 g8 = *(const short8*)(gr + c0);
    float4 wa = *(const float4*)(wtab + k * 64 + h0);
    float4 wb = *(const float4*)(wtab + k * 64 + h0 + 4);
    float4 na = *(const float4*)(gnw + c0);
    float4 nb = *(const float4*)(gnw + c0 + 4);
    float wreg[8] = {wa.x, wa.y, wa.z, wa.w, wb.x, wb.y, wb.z, wb.w};
    float nreg[8] = {na.x, na.y, na.z, na.w, nb.x, nb.y, nb.z, nb.w};

    float vals[8];
    float ss = 0.0f;
#pragma unroll
    for (int j = 0; j < 8; j++) {
        float sre = s2f(re8[j]) * idn;
        float sim = s2f(im8[j]) * idn;
        short qre_s = (j < 4) ? qa[2 * j] : qb[2 * (j - 4)];
        short qim_s = (j < 4) ? qa[2 * j + 1] : qb[2 * (j - 4) + 1];
        float qre = s2f(qre_s);
        float qim = s2f(qim_s);
        float m = is_im ? (sim * qre - sre * qim) : (sre * qre + sim * qim);
        m *= 0.125f * wreg[j];
        float hv = m * fsilu(s2f(g8[j]));
        vals[j] = hv;
        ss += hv * hv;
    }
    const int lane = threadIdx.x & 63;
    const int wv_id = threadIdx.x >> 6;
#pragma unroll
    for (int off = 32; off > 0; off >>= 1) ss += __shfl_down(ss, off);
    if (lane == 0) wsum[wv_id] = ss;
    __syncthreads();
    float total = wsum[0] + wsum[1] + wsum[2];
    float inv_rms = rsqrtf(total * (1.0f / (float)OUT_CPLX) + 1e-6f);
    short8 o;
#pragma unroll
    for (int j = 0; j < 8; j++) o[j] = f2s(vals[j] * inv_rms * nreg[j]);
    *(short8*)(csr + c0) = o;
}

__global__ void sentinel_kernel(float* out, float v)
{
    if (threadIdx.x == 0) out[0] = v;
}

// ---------------------------------------------------------------------------
// Workspace layout (bytes)
// ---------------------------------------------------------------------------
#define XB_OFF 0UL                 // 16384x768 bf16       25,165,824
#define WT_IN_OFF 25165824UL       // 1792x768 bf16         2,752,512 (rows 1548+ unwritten, clipped)
#define WT_GATE_OFF 27918336UL     // 1536x768 bf16         2,359,296
#define WT_OUT_OFF 30277632UL      // 768x2304 bf16         3,538,944
#define WT_RO_OFF 33816576UL       // 12x384x128 bf16       1,179,648
#define SUMS_OFF 34996224UL        // 512x1552 fp32         3,178,496
#define WTAB_OFF 38174720UL        // 768 fp32                  3,072
#define CS_OFF 38177792UL          // 16384x1552 bf16      50,855,936
#define A_OFF 89033728UL           // z0 16384x1552 bf16; later gate; later y (75,497,472)
#define QBUF_OFF 139889664UL       // 16384x768 bf16       25,165,824 (overlapped by y tail later)
#define WS_NEEDED 165055488UL      // < 166,932,480 proven available

extern "C" void kernel_launch(void* const* d_in, const int* in_sizes, int n_in,
                              void* d_out, int out_size, void* d_ws, size_t ws_size,
                              hipStream_t stream)
{
    const float* x = (const float*)d_in[0];
    const float* W_in = (const float*)d_in[1];
    const float* conv_w = (const float*)d_in[2];
    const float* theta_raw = (const float*)d_in[3];
    const float* w_int_raw = (const float*)d_in[4];
    const float* decay_slopes = (const float*)d_in[5];
    const float* score_scale = (const float*)d_in[6];
    const float* score_bias = (const float*)d_in[7];
    const float* phase_scale = (const float*)d_in[8];
    const float* gnw = (const float*)d_in[9];
    const float* W_readout = (const float*)d_in[10];
    const float* W_gate = (const float*)d_in[11];
    const float* W_out = (const float*)d_in[12];

    if (ws_size < WS_NEEDED) {
        sentinel_kernel<<<1, 64, 0, stream>>>((float*)d_out, (float)ws_size);
        return;
    }

    char* ws = (char*)d_ws;
    bf16* xb = (bf16*)(ws + XB_OFF);
    bf16* WT_IN = (bf16*)(ws + WT_IN_OFF);
    bf16* WT_GATE = (bf16*)(ws + WT_GATE_OFF);
    bf16* WT_OUT = (bf16*)(ws + WT_OUT_OFF);
    bf16* WT_RO = (bf16*)(ws + WT_RO_OFF);
    float* sums = (float*)(ws + SUMS_OFF);
    float* wtab = (float*)(ws + WTAB_OFF);
    bf16* cs = (bf16*)(ws + CS_OFF);
    bf16* z0 = (bf16*)(ws + A_OFF);
    bf16* gate = (bf16*)(ws + A_OFF);
    bf16* y = (bf16*)(ws + A_OFF);
    bf16* qbuf = (bf16*)(ws + QBUF_OFF);

    // 0. single prep launch: convert x, wint table, all weight transposes
    prep_kernel<<<PREP_TOTAL, 256, 0, stream>>>(
        x, w_int_raw, W_in, W_gate, W_out, W_readout,
        xb, wtab, WT_IN, WT_GATE, WT_OUT, WT_RO);

    // 1. z0 = x @ W_in (axis-swapped grid: N-tiles fast -> A-panel L2 reuse)
    gemm_kernel<true, true><<<dim3(13, 128), 256, 0, stream>>>(xb, 768, WT_IN, 768,
                                                               z0, Z_LD, 768, 1548);

    // 2. terms (pw fused in-block) + chunk sums; parallel chunk scan; cumsum
    scan_terms<<<512, 256, 0, stream>>>(z0, conv_w, theta_raw, phase_scale,
                                        decay_slopes, score_scale, score_bias,
                                        cs, qbuf, sums);
    scan_mid<<<dim3(25, 4), 256, 0, stream>>>(sums);
    scan_inplace<<<512, 256, 0, stream>>>(cs, sums);

    // 3. gate = x @ W_gate (axis-swapped, overwrites z0)
    gemm_kernel<true, true><<<dim3(12, 128), 256, 0, stream>>>(xb, 768, WT_GATE, 768,
                                                               gate, 1536, 768, 1536);

    // 4. match + gated rmsnorm -> out_n in-place into cs
    match_norm_kernel<<<NROW, 192, 0, stream>>>(cs, qbuf, gate, wtab, gnw);

    // 5. readout GEMM + fused GLU v2 -> y
    gemm_readout_glu<<<dim3(128, 3, 12), 256, 0, stream>>>(
        cs, CS_LD, 128L, WT_RO, 128, 49152L, y, 128);

    // 6. out = y @ W_out (axis-swapped)
    gemm_kernel<false, true><<<dim3(6, 128), 256, 0, stream>>>(y, 2304, WT_OUT, 2304,
                                                               (float*)d_out, 768, 2304, 768);
}

// Round 8
// 412.232 us; speedup vs baseline: 1.1233x; 1.1233x over previous
//
#include <hip/hip_runtime.h>
#include <hip/hip_bf16.h>

typedef __hip_bfloat16 bf16;
typedef __attribute__((ext_vector_type(8))) short short8;
typedef __attribute__((ext_vector_type(4))) float floatx4;

#define L_SEQ 4096
#define B_SZ 4
#define NROW 16384          // B*L
#define NK 12
#define DIM_CONV 1548
#define Z_LD 1552           // z0 row stride: [0,768)=kv, [768,1536)=q, [1536,1548)=s
#define OUT_CPLX 1536
#define CS_LD 1552          // cs row stride: [0,768)=re, [768,1536)=im, [1536,1548)=pw
#define NCHUNK 128
#define CLEN 32

__device__ __forceinline__ float bf2f(bf16 v) { return __bfloat162float(v); }
__device__ __forceinline__ float s2f(short v) {
    unsigned u = ((unsigned)(unsigned short)v) << 16;
    return __builtin_bit_cast(float, u);
}
__device__ __forceinline__ short f2s(float x) {
    bf16 b = __float2bfloat16(x);
    return __builtin_bit_cast(short, b);
}
__device__ __forceinline__ float frcp(float x) { return __builtin_amdgcn_rcpf(x); }
__device__ __forceinline__ float fsigmoid(float x) { return frcp(1.0f + __expf(-x)); }
__device__ __forceinline__ float fsilu(float x) { return x * fsigmoid(x); }
__device__ __forceinline__ float fsoftplus(float x) {
    return fmaxf(x, 0.0f) + __logf(1.0f + __expf(-fabsf(x)));
}

// ---------------------------------------------------------------------------
// GEMM core v2 (128x128 tile, 64x64 wave tile, BK=64, XOR swizzle).
// 124 regs/wave (60 VGPR + 64 AGPR acc), 32 KB LDS -> up to 4 blocks/CU.
//
// GRID NOTE (r7 lesson): use grid (Mtiles, Ntiles) with mb = blockIdx.x.
// XCD = linear_bid % 8; with Mtiles = 128 (multiple of 8), XCD = mb % 8 —
// each XCD statically owns Mtiles/8 A-panels for ALL nb rounds (fits 4 MB
// L2). The r7 axis-swap scattered panel-sharing blocks across XCDs and
// blew FETCH up 52 -> 230 MB (private L2s duplicate panels 8x).
// ---------------------------------------------------------------------------
#define GEMM_CORE2(A_, lda_, Bt_, ldb_, Kd_)                                             \
    __shared__ __align__(16) short lds_a[128 * 64];                                      \
    __shared__ __align__(16) short lds_b[128 * 64];                                      \
    const int tid = threadIdx.x;                                                         \
    const int wave = tid >> 6;                                                           \
    const int lane = tid & 63;                                                           \
    const bf16* ga[4];                                                                   \
    const bf16* gb[4];                                                                   \
    short* la[4];                                                                        \
    short* lb[4];                                                                        \
    _Pragma("unroll") for (int s = 0; s < 4; s++) {                                      \
        int p = s * 256 + tid;                                                           \
        int row = p >> 3;                                                                \
        int k8 = (p & 7) ^ (row & 7);                                                    \
        ga[s] = A_ + (size_t)row * lda_ + k8 * 8;                                        \
        gb[s] = Bt_ + (size_t)row * ldb_ + k8 * 8;                                       \
        la[s] = lds_a + (size_t)(s * 256 + wave * 64) * 8;                               \
        lb[s] = lds_b + (size_t)(s * 256 + wave * 64) * 8;                               \
    }                                                                                    \
    floatx4 acc[4][4];                                                                   \
    _Pragma("unroll") for (int i = 0; i < 4; i++)                                        \
        _Pragma("unroll") for (int j = 0; j < 4; j++)                                    \
            acc[i][j] = (floatx4){0.f, 0.f, 0.f, 0.f};                                   \
    const int wm = (wave >> 1) * 64;                                                     \
    const int wn = (wave & 1) * 64;                                                      \
    const int lrow = lane & 15;                                                          \
    const int lk8 = lane >> 4;                                                           \
    for (int k0 = 0; k0 < Kd_; k0 += 64) {                                               \
        _Pragma("unroll") for (int s = 0; s < 4; s++) {                                  \
            __builtin_amdgcn_global_load_lds((const __attribute__((address_space(1))) void*)ga[s], \
                                             (__attribute__((address_space(3))) void*)la[s], 16, 0, 0); \
            __builtin_amdgcn_global_load_lds((const __attribute__((address_space(1))) void*)gb[s], \
                                             (__attribute__((address_space(3))) void*)lb[s], 16, 0, 0); \
            ga[s] += 64; gb[s] += 64;                                                    \
        }                                                                                \
        __syncthreads();                                                                 \
        _Pragma("unroll") for (int s2 = 0; s2 < 2; s2++) {                               \
            short8 af[4], bfv[4];                                                        \
            const int k8L = s2 * 4 + lk8;                                                \
            _Pragma("unroll") for (int i = 0; i < 4; i++) {                              \
                int m = wm + i * 16 + lrow;                                              \
                af[i] = *(const short8*)(lds_a + ((size_t)m * 8 + (k8L ^ (m & 7))) * 8); \
            }                                                                            \
            _Pragma("unroll") for (int j = 0; j < 4; j++) {                              \
                int n = wn + j * 16 + lrow;                                              \
                bfv[j] = *(const short8*)(lds_b + ((size_t)n * 8 + (k8L ^ (n & 7))) * 8); \
            }                                                                            \
            _Pragma("unroll") for (int i = 0; i < 4; i++)                                \
                _Pragma("unroll") for (int j = 0; j < 4; j++)                            \
                    acc[i][j] = __builtin_amdgcn_mfma_f32_16x16x32_bf16(af[i], bfv[j], acc[i][j], 0, 0, 0); \
        }                                                                                \
        __syncthreads();                                                                 \
    }

template <bool OUT_BF16>
__global__ __launch_bounds__(256, 4) void gemm_kernel(
    const bf16* __restrict__ A, int lda,
    const bf16* __restrict__ Bt, int ldb,
    void* __restrict__ Cv, int ldc, int Kd, int nmax)
{
    const bf16* Ab = A + (size_t)blockIdx.x * 128 * lda;
    const bf16* Bb = Bt + (size_t)blockIdx.y * 128 * ldb;
    GEMM_CORE2(Ab, lda, Bb, ldb, Kd)
    const int orow = blockIdx.x * 128 + wm + (lk8 << 2);
    const int ocol = blockIdx.y * 128 + wn + lrow;
    if (OUT_BF16) {
        bf16* C = (bf16*)Cv;
#pragma unroll
        for (int i = 0; i < 4; i++)
#pragma unroll
            for (int j = 0; j < 4; j++)
                if (ocol + j * 16 < nmax)
#pragma unroll
                    for (int r = 0; r < 4; r++)
                        C[(size_t)(orow + i * 16 + r) * ldc + (ocol + j * 16)] =
                            __float2bfloat16(acc[i][j][r]);
    } else {
        float* C = (float*)Cv;
#pragma unroll
        for (int i = 0; i < 4; i++)
#pragma unroll
            for (int j = 0; j < 4; j++)
                if (ocol + j * 16 < nmax)
#pragma unroll
                    for (int r = 0; r < 4; r++)
                        C[(size_t)(orow + i * 16 + r) * ldc + (ocol + j * 16)] = acc[i][j][r];
    }
}

// ---------------------------------------------------------------------------
// Readout GEMM + fused GLU, v2: WT_RO uses 16-col-block interleave so a
// thread's acc[i][2p]=val and acc[i][2p+1]=gate are in the SAME lane ->
// GLU with no shuffle and half the sigmoids. Output staged through LDS
// (XOR-swizzled, conflict-free) then written as coalesced short8 — global
// store instructions 32 -> 4 per thread. (r6 profile: v1 was MfmaUtil 12%,
// VALUBusy 42% — epilogue-bound at 300 TF.)
// ---------------------------------------------------------------------------
__global__ __launch_bounds__(256, 3) void gemm_readout_glu(
    const bf16* __restrict__ A, int lda, long a_zoff,
    const bf16* __restrict__ Bt, int ldb, long b_zoff,
    bf16* __restrict__ Y, int Kd)
{
    const int z = blockIdx.z;
    const bf16* Ab = A + (long)z * a_zoff + (size_t)blockIdx.x * 128 * lda;
    const bf16* Bb = Bt + (long)z * b_zoff + (size_t)blockIdx.y * 128 * ldb;
    GEMM_CORE2(Ab, lda, Bb, ldb, Kd)
    // GLU into LDS stage (reuse lds_a; K-loop's trailing barrier covers reuse)
    const int colb = wn >> 1;
#pragma unroll
    for (int i = 0; i < 4; i++) {
        const int row0 = wm + i * 16 + (lk8 << 2);
#pragma unroll
        for (int p = 0; p < 2; p++) {
            const int col = colb + p * 16 + lrow;
#pragma unroll
            for (int r = 0; r < 4; r++) {
                const int row = row0 + r;
                float v = acc[i][2 * p][r];
                float g = acc[i][2 * p + 1][r];
                lds_a[row * 64 + (col ^ ((row & 12) << 2))] = f2s(v * fsigmoid(g));
            }
        }
    }
    __syncthreads();
    bf16* Yk = Y + (long)z * 192 + (size_t)blockIdx.x * 128 * 2304 + (size_t)blockIdx.y * 64;
#pragma unroll
    for (int ch = tid; ch < 1024; ch += 256) {
        const int row = ch >> 3;
        const int c8 = (ch & 7) * 8;
        *(short8*)(Yk + (size_t)row * 2304 + c8) =
            *(const short8*)(lds_a + row * 64 + (c8 ^ ((row & 12) << 2)));
    }
}

// ---------------------------------------------------------------------------
// prep_kernel: ONE launch for x->bf16 convert, w_int table, and all 7 weight
// transposes (fp32->bf16, tiled 32x32 via LDS). blockIdx.x range-dispatched.
// gmode: 0 = plain transpose row=c; 1/2 = W_readout 16-col-block interleave
// (val -> (c>>4)*32+(c&15), gate -> +16) matching gemm_readout_glu v2.
// ---------------------------------------------------------------------------
#define PREP_CONV_BLKS 6144
#define PREP_WINT_BLKS 3
#define PREP_T0 (PREP_CONV_BLKS + PREP_WINT_BLKS)   // 6147
#define PREP_TOTAL (PREP_T0 + 4632)                  // 10779

__global__ __launch_bounds__(256) void prep_kernel(
    const float* __restrict__ x, const float* __restrict__ w_int_raw,
    const float* __restrict__ W_in, const float* __restrict__ W_gate,
    const float* __restrict__ W_out, const float* __restrict__ W_readout,
    bf16* __restrict__ xb, float* __restrict__ wtab,
    bf16* __restrict__ WT_IN, bf16* __restrict__ WT_GATE,
    bf16* __restrict__ WT_OUT, bf16* __restrict__ WT_RO)
{
    __shared__ float tle[32][33];
    const int blk = blockIdx.x;
    const int tid = threadIdx.x;

    if (blk < PREP_CONV_BLKS) {
        long gid = ((long)blk * 256 + tid) * 8;
        float4 a = *(const float4*)(x + gid);
        float4 b = *(const float4*)(x + gid + 4);
        short8 o;
        o[0] = f2s(a.x); o[1] = f2s(a.y); o[2] = f2s(a.z); o[3] = f2s(a.w);
        o[4] = f2s(b.x); o[5] = f2s(b.y); o[6] = f2s(b.z); o[7] = f2s(b.w);
        *(short8*)(xb + gid) = o;
        return;
    }
    if (blk < PREP_T0) {
        int i = (blk - PREP_CONV_BLKS) * 256 + tid;
        if (i < 768) {
            float e = __expf(w_int_raw[i]);
            wtab[i] = e * frcp(e + 1e-6f);
        }
        return;
    }
    int t = blk - PREP_T0;
    const float* in; bf16* out;
    int ld_in, ld_out, R, C, gmode, nx;
    if (t < 576) {                       // W_in kv cols -> WT_IN rows 0..767
        in = W_in; out = WT_IN; ld_in = 1548; ld_out = 768;
        R = 768; C = 768; gmode = 0; nx = 24;
    } else if (t < 1152) {               // W_in q cols 780.. -> rows 768..1535
        t -= 576;
        in = W_in + 780; out = WT_IN + 768L * 768; ld_in = 1548; ld_out = 768;
        R = 768; C = 768; gmode = 0; nx = 24;
    } else if (t < 1176) {               // W_in s cols 768..779 -> rows 1536..1547
        t -= 1152;
        in = W_in + 768; out = WT_IN + 1536L * 768; ld_in = 1548; ld_out = 768;
        R = 768; C = 12; gmode = 0; nx = 1;
    } else if (t < 2328) {               // W_gate
        t -= 1176;
        in = W_gate; out = WT_GATE; ld_in = 1536; ld_out = 768;
        R = 768; C = 1536; gmode = 0; nx = 48;
    } else if (t < 4056) {               // W_out
        t -= 2328;
        in = W_out; out = WT_OUT; ld_in = 768; ld_out = 2304;
        R = 2304; C = 768; gmode = 0; nx = 24;
    } else if (t < 4344) {               // W_readout val half (16-blk interleave)
        t -= 4056;
        int k = t / 24; t %= 24;
        in = W_readout + (long)k * 49152; out = WT_RO + (long)k * 49152;
        ld_in = 384; ld_out = 128; R = 128; C = 192; gmode = 1; nx = 6;
    } else {                             // W_readout gate half
        t -= 4344;
        int k = t / 24; t %= 24;
        in = W_readout + (long)k * 49152 + 192; out = WT_RO + (long)k * 49152;
        ld_in = 384; ld_out = 128; R = 128; C = 192; gmode = 2; nx = 6;
    }
    int c0 = (t % nx) * 32, r0 = (t / nx) * 32;
    int tx = tid & 31, ty = tid >> 5;    // 32x8
#pragma unroll
    for (int i = 0; i < 32; i += 8) {
        int r = r0 + ty + i, c = c0 + tx;
        if (r < R && c < C) tle[ty + i][tx] = in[(size_t)r * ld_in + c];
    }
    __syncthreads();
#pragma unroll
    for (int i = 0; i < 32; i += 8) {
        int c = c0 + ty + i, r = r0 + tx;
        if (c < C && r < R) {
            int orow2 = (gmode == 0) ? c
                       : ((c & 15) + ((c >> 4) << 5) + ((gmode == 2) ? 16 : 0));
            out[(size_t)orow2 * ld_out + r] = __float2bfloat16(tle[tx][ty + i]);
        }
    }
}

// ---------------------------------------------------------------------------
// scan_terms (pw fused): one block per rest=(b,chunk).
// ---------------------------------------------------------------------------
__global__ __launch_bounds__(256) void scan_terms(
    const bf16* __restrict__ z0, const float* __restrict__ conv_w,
    const float* __restrict__ theta_raw, const float* __restrict__ pscale,
    const float* __restrict__ decay, const float* __restrict__ sscale,
    const float* __restrict__ sbias,
    bf16* __restrict__ cs, bf16* __restrict__ qbuf, float* __restrict__ sums)
{
    __shared__ float pwl[CLEN][NK];
    const int rest = blockIdx.x;              // b*128 + chunk
    const int chunk = rest & (NCHUNK - 1);
    const int b = rest >> 7;
    const int l0 = chunk * CLEN;
    const int tau = threadIdx.x;
    const bf16* zb = z0 + (size_t)b * L_SEQ * Z_LD;
    bf16* csb = cs + (size_t)b * L_SEQ * CS_LD;
    const size_t bL = (size_t)b * L_SEQ;
    float* srow = sums + (size_t)rest * 1552;

    if (tau < NK) {
        const int k = tau;
        const int zc = 1536 + k;
        const int wc = 768 + k;
        float w0 = conv_w[0 * DIM_CONV + wc], w1 = conv_w[1 * DIM_CONV + wc];
        float w2 = conv_w[2 * DIM_CONV + wc], w3 = conv_w[3 * DIM_CONV + wc];
        float ss = sscale[k], sb = sbias[k];
        float slope = fsoftplus(decay[k]);
        float h1 = (l0 >= 3) ? bf2f(zb[(size_t)(l0 - 3) * Z_LD + zc]) : 0.f;
        float h2 = (l0 >= 2) ? bf2f(zb[(size_t)(l0 - 2) * Z_LD + zc]) : 0.f;
        float h3 = (l0 >= 1) ? bf2f(zb[(size_t)(l0 - 1) * Z_LD + zc]) : 0.f;
        for (int i = 0; i < CLEN; i++) {
            int l = l0 + i;
            float cur = bf2f(zb[(size_t)l * Z_LD + zc]);
            float s = fsilu(w0 * h1 + w1 * h2 + w2 * h3 + w3 * cur);
            h1 = h2; h2 = h3; h3 = cur;
            float pw = fsoftplus(ss * s + sb) * __expf(-slope * (float)(L_SEQ - 1 - l));
            pwl[i][k] = fminf(fmaxf(pw, 1e-4f), 5000.0f);
        }
    }
    __syncthreads();
    if (tau >= 194) return;

    if (tau < 96) {
        const int cv0 = tau * 8;
        const int k = cv0 >> 6;
        float wt[4][8], th[8];
#pragma unroll
        for (int t = 0; t < 4; t++)
#pragma unroll
            for (int j = 0; j < 8; j++) wt[t][j] = conv_w[t * DIM_CONV + cv0 + j];
#pragma unroll
        for (int j = 0; j < 8; j++)
            th[j] = 0.001f + 2.999f * fsigmoid(theta_raw[cv0 + j]);
        const float ps = pscale[k];
        float h1[8], h2[8], h3[8];
#pragma unroll
        for (int j = 0; j < 8; j++) { h1[j] = 0.f; h2[j] = 0.f; h3[j] = 0.f; }
        if (l0 >= 1) {
            short8 v = *(const short8*)(zb + (size_t)(l0 - 1) * Z_LD + cv0);
#pragma unroll
            for (int j = 0; j < 8; j++) h3[j] = s2f(v[j]);
            short8 u = *(const short8*)(zb + (size_t)(l0 - 2) * Z_LD + cv0);
#pragma unroll
            for (int j = 0; j < 8; j++) h2[j] = s2f(u[j]);
            short8 w = *(const short8*)(zb + (size_t)(l0 - 3) * Z_LD + cv0);
#pragma unroll
            for (int j = 0; j < 8; j++) h1[j] = s2f(w[j]);
        }
        float sre[8], sim[8];
#pragma unroll
        for (int j = 0; j < 8; j++) { sre[j] = 0.f; sim[j] = 0.f; }
        for (int i = 0; i < CLEN; i++) {
            int l = l0 + i;
            short8 zv = *(const short8*)(zb + (size_t)l * Z_LD + cv0);
            float pw = pwl[i][k];
            short8 vr, vi;
#pragma unroll
            for (int j = 0; j < 8; j++) {
                float cur = s2f(zv[j]);
                float kv = fsilu(wt[0][j] * h1[j] + wt[1][j] * h2[j] + wt[2][j] * h3[j] + wt[3][j] * cur);
                h1[j] = h2[j]; h2[j] = h3[j]; h3[j] = cur;
                float ksv = kv * ps;
                float phi = ksv * frcp(1.0f + fabsf(ksv)) * th[j];
                float sn = __sinf(phi);
                float cn = __cosf(phi);
                float kvw = kv * pw;
                short tr = f2s(kvw * cn);
                short ti = f2s(kvw * sn);
                vr[j] = tr; vi[j] = ti;
                sre[j] += s2f(tr);
                sim[j] += s2f(ti);
            }
            *(short8*)(csb + (size_t)l * CS_LD + cv0) = vr;
            *(short8*)(csb + (size_t)l * CS_LD + 768 + cv0) = vi;
        }
#pragma unroll
        for (int j = 0; j < 8; j++) {
            srow[cv0 + j] = sre[j];
            srow[768 + cv0 + j] = sim[j];
        }
    } else if (tau < 192) {
        const int qc0 = (tau - 96) * 8;
        const int zc0 = 768 + qc0;
        const int wc0 = 780 + qc0;
        float wt[4][8];
#pragma unroll
        for (int t = 0; t < 4; t++)
#pragma unroll
            for (int j = 0; j < 8; j++) wt[t][j] = conv_w[t * DIM_CONV + wc0 + j];
        float h1[8], h2[8], h3[8];
#pragma unroll
        for (int j = 0; j < 8; j++) { h1[j] = 0.f; h2[j] = 0.f; h3[j] = 0.f; }
        if (l0 >= 1) {
            short8 v = *(const short8*)(zb + (size_t)(l0 - 1) * Z_LD + zc0);
#pragma unroll
            for (int j = 0; j < 8; j++) h3[j] = s2f(v[j]);
            short8 u = *(const short8*)(zb + (size_t)(l0 - 2) * Z_LD + zc0);
#pragma unroll
            for (int j = 0; j < 8; j++) h2[j] = s2f(u[j]);
            short8 w = *(const short8*)(zb + (size_t)(l0 - 3) * Z_LD + zc0);
#pragma unroll
            for (int j = 0; j < 8; j++) h1[j] = s2f(w[j]);
        }
        for (int i = 0; i < CLEN; i++) {
            int l = l0 + i;
            short8 zv = *(const short8*)(zb + (size_t)l * Z_LD + zc0);
            short8 o;
#pragma unroll
            for (int j = 0; j < 8; j++) {
                float cur = s2f(zv[j]);
                float q = fsilu(wt[0][j] * h1[j] + wt[1][j] * h2[j] + wt[2][j] * h3[j] + wt[3][j] * cur);
                h1[j] = h2[j]; h2[j] = h3[j]; h3[j] = cur;
                o[j] = f2s(q);
            }
            *(short8*)(qbuf + (bL + l) * 768 + qc0) = o;
        }
    } else {
        const int k0 = (tau == 192) ? 0 : 8;
        const int nv = (tau == 192) ? 8 : 4;
        float spw[8];
#pragma unroll
        for (int j = 0; j < 8; j++) spw[j] = 0.f;
        for (int i = 0; i < CLEN; i++) {
            int l = l0 + i;
            short8 o;
#pragma unroll
            for (int j = 0; j < 8; j++) {
                float v = (j < nv) ? pwl[i][k0 + j] : 0.0f;
                short t = f2s(v);
                o[j] = t;
                spw[j] += s2f(t);
            }
            *(short8*)(csb + (size_t)l * CS_LD + 1536 + k0) = o;
        }
#pragma unroll
        for (int j = 0; j < 8; j++) srow[1536 + k0 + j] = spw[j];
    }
}

// ---------------------------------------------------------------------------
// scan_mid v2: parallel LDS-tiled exclusive scan over NCHUNK chunks.
// ---------------------------------------------------------------------------
#define SMID_COLS 64
__global__ __launch_bounds__(256) void scan_mid(float* __restrict__ sums)
{
    __shared__ float tle[NCHUNK][SMID_COLS];   // 32 KB
    const int b = blockIdx.y;
    const int c0 = blockIdx.x * SMID_COLS;
    const int tc = threadIdx.x & 63;
    const int tr = threadIdx.x >> 6;           // 0..3
    const int c = c0 + tc;
    const bool valid = (c < 1552);
    if (valid) {
#pragma unroll
        for (int i = tr; i < NCHUNK; i += 4)
            tle[i][tc] = sums[((size_t)(b * NCHUNK + i)) * 1552 + c];
    }
    __syncthreads();
    if (threadIdx.x < 64 && valid) {
        float run = 0.f;
        for (int i = 0; i < NCHUNK; i++) {
            float v = tle[i][tc];
            tle[i][tc] = run;
            run += v;
        }
    }
    __syncthreads();
    if (valid) {
#pragma unroll
        for (int i = tr; i < NCHUNK; i += 4)
            sums[((size_t)(b * NCHUNK + i)) * 1552 + c] = tle[i][tc];
    }
}

// in-place cumsum over bf16 terms, 8 cols/thread, 16B loads/stores
__global__ __launch_bounds__(256) void scan_inplace(
    bf16* __restrict__ cs, const float* __restrict__ sums)
{
    const int rest = blockIdx.x;
    const int chunk = rest & (NCHUNK - 1);
    const int b = rest >> 7;
    const int tau = threadIdx.x;
    if (tau >= 194) return;
    const int c0 = tau * 8;
    float run[8];
    const float* srow = sums + (size_t)rest * 1552;
#pragma unroll
    for (int j = 0; j < 8; j++) run[j] = srow[c0 + j];
    bf16* p = cs + ((size_t)(b * L_SEQ + chunk * CLEN)) * CS_LD + c0;
    for (int i = 0; i < CLEN; i++) {
        short8 v = *(const short8*)p;
        short8 o;
#pragma unroll
        for (int j = 0; j < 8; j++) {
            run[j] += s2f(v[j]);
            o[j] = f2s(run[j]);
        }
        *(short8*)p = o;
        p += CS_LD;
    }
}

// ---------------------------------------------------------------------------
// match + gated RMSNorm, vectorized: block=192 threads, 8 cols/thread.
// ---------------------------------------------------------------------------
__global__ __launch_bounds__(192) void match_norm_kernel(
    bf16* __restrict__ cs, const bf16* __restrict__ qbuf,
    const bf16* __restrict__ gate, const float* __restrict__ wtab,
    const float* __restrict__ gnw)
{
    const int bl = blockIdx.x;
    bf16* csr = cs + (size_t)bl * CS_LD;
    const bf16* qr = qbuf + (size_t)bl * 768;
    const bf16* gr = gate + (size_t)bl * OUT_CPLX;
    __shared__ float inv_den[NK];
    __shared__ float wsum[3];

    if (threadIdx.x < NK)
        inv_den[threadIdx.x] = 1.0f / fmaxf(bf2f(csr[1536 + threadIdx.x]), 1e-4f);
    __syncthreads();

    const int c0 = threadIdx.x * 8;
    const int k = c0 >> 7;
    const int r0 = c0 & 127;
    const int h0 = r0 & 63;
    const bool is_im = (r0 >= 64);
    const int kq = k >> 1;
    const float idn = inv_den[k];

    short8 re8 = *(const short8*)(csr + k * 64 + h0);
    short8 im8 = *(const short8*)(csr + 768 + k * 64 + h0);
    short8 qa = *(const short8*)(qr + kq * 128 + 2 * h0);
    short8 qb = *(const short8*)(qr + kq * 128 + 2 * h0 + 8);
    short8 g8 = *(const short8*)(gr + c0);
    float4 wa = *(const float4*)(wtab + k * 64 + h0);
    float4 wb = *(const float4*)(wtab + k * 64 + h0 + 4);
    float4 na = *(const float4*)(gnw + c0);
    float4 nb = *(const float4*)(gnw + c0 + 4);
    float wreg[8] = {wa.x, wa.y, wa.z, wa.w, wb.x, wb.y, wb.z, wb.w};
    float nreg[8] = {na.x, na.y, na.z, na.w, nb.x, nb.y, nb.z, nb.w};

    float vals[8];
    float ss = 0.0f;
#pragma unroll
    for (int j = 0; j < 8; j++) {
        float sre = s2f(re8[j]) * idn;
        float sim = s2f(im8[j]) * idn;
        short qre_s = (j < 4) ? qa[2 * j] : qb[2 * (j - 4)];
        short qim_s = (j < 4) ? qa[2 * j + 1] : qb[2 * (j - 4) + 1];
        float qre = s2f(qre_s);
        float qim = s2f(qim_s);
        float m = is_im ? (sim * qre - sre * qim) : (sre * qre + sim * qim);
        m *= 0.125f * wreg[j];
        float hv = m * fsilu(s2f(g8[j]));
        vals[j] = hv;
        ss += hv * hv;
    }
    const int lane = threadIdx.x & 63;
    const int wv_id = threadIdx.x >> 6;
#pragma unroll
    for (int off = 32; off > 0; off >>= 1) ss += __shfl_down(ss, off);
    if (lane == 0) wsum[wv_id] = ss;
    __syncthreads();
    float total = wsum[0] + wsum[1] + wsum[2];
    float inv_rms = rsqrtf(total * (1.0f / (float)OUT_CPLX) + 1e-6f);
    short8 o;
#pragma unroll
    for (int j = 0; j < 8; j++) o[j] = f2s(vals[j] * inv_rms * nreg[j]);
    *(short8*)(csr + c0) = o;
}

__global__ void sentinel_kernel(float* out, float v)
{
    if (threadIdx.x == 0) out[0] = v;
}

// ---------------------------------------------------------------------------
// Workspace layout (bytes)
// ---------------------------------------------------------------------------
#define XB_OFF 0UL                 // 16384x768 bf16       25,165,824
#define WT_IN_OFF 25165824UL       // 1792x768 bf16         2,752,512 (rows 1548+ unwritten, clipped)
#define WT_GATE_OFF 27918336UL     // 1536x768 bf16         2,359,296
#define WT_OUT_OFF 30277632UL      // 768x2304 bf16         3,538,944
#define WT_RO_OFF 33816576UL       // 12x384x128 bf16       1,179,648
#define SUMS_OFF 34996224UL        // 512x1552 fp32         3,178,496
#define WTAB_OFF 38174720UL        // 768 fp32                  3,072
#define CS_OFF 38177792UL          // 16384x1552 bf16      50,855,936
#define A_OFF 89033728UL           // z0 16384x1552 bf16; later gate; later y (75,497,472)
#define QBUF_OFF 139889664UL       // 16384x768 bf16       25,165,824 (overlapped by y tail later)
#define WS_NEEDED 165055488UL      // < 166,932,480 proven available

extern "C" void kernel_launch(void* const* d_in, const int* in_sizes, int n_in,
                              void* d_out, int out_size, void* d_ws, size_t ws_size,
                              hipStream_t stream)
{
    const float* x = (const float*)d_in[0];
    const float* W_in = (const float*)d_in[1];
    const float* conv_w = (const float*)d_in[2];
    const float* theta_raw = (const float*)d_in[3];
    const float* w_int_raw = (const float*)d_in[4];
    const float* decay_slopes = (const float*)d_in[5];
    const float* score_scale = (const float*)d_in[6];
    const float* score_bias = (const float*)d_in[7];
    const float* phase_scale = (const float*)d_in[8];
    const float* gnw = (const float*)d_in[9];
    const float* W_readout = (const float*)d_in[10];
    const float* W_gate = (const float*)d_in[11];
    const float* W_out = (const float*)d_in[12];

    if (ws_size < WS_NEEDED) {
        sentinel_kernel<<<1, 64, 0, stream>>>((float*)d_out, (float)ws_size);
        return;
    }

    char* ws = (char*)d_ws;
    bf16* xb = (bf16*)(ws + XB_OFF);
    bf16* WT_IN = (bf16*)(ws + WT_IN_OFF);
    bf16* WT_GATE = (bf16*)(ws + WT_GATE_OFF);
    bf16* WT_OUT = (bf16*)(ws + WT_OUT_OFF);
    bf16* WT_RO = (bf16*)(ws + WT_RO_OFF);
    float* sums = (float*)(ws + SUMS_OFF);
    float* wtab = (float*)(ws + WTAB_OFF);
    bf16* cs = (bf16*)(ws + CS_OFF);
    bf16* z0 = (bf16*)(ws + A_OFF);
    bf16* gate = (bf16*)(ws + A_OFF);
    bf16* y = (bf16*)(ws + A_OFF);
    bf16* qbuf = (bf16*)(ws + QBUF_OFF);

    // 0. single prep launch: convert x, wint table, all weight transposes
    prep_kernel<<<PREP_TOTAL, 256, 0, stream>>>(
        x, w_int_raw, W_in, W_gate, W_out, W_readout,
        xb, wtab, WT_IN, WT_GATE, WT_OUT, WT_RO);

    // 1. z0 = x @ W_in (grid (128, N): XCD = mb%8 -> per-XCD A-panel affinity)
    gemm_kernel<true><<<dim3(128, 13), 256, 0, stream>>>(xb, 768, WT_IN, 768,
                                                         z0, Z_LD, 768, 1548);

    // 2. terms (pw fused in-block) + chunk sums; parallel chunk scan; cumsum
    scan_terms<<<512, 256, 0, stream>>>(z0, conv_w, theta_raw, phase_scale,
                                        decay_slopes, score_scale, score_bias,
                                        cs, qbuf, sums);
    scan_mid<<<dim3(25, 4), 256, 0, stream>>>(sums);
    scan_inplace<<<512, 256, 0, stream>>>(cs, sums);

    // 3. gate = x @ W_gate (overwrites z0)
    gemm_kernel<true><<<dim3(128, 12), 256, 0, stream>>>(xb, 768, WT_GATE, 768,
                                                         gate, 1536, 768, 1536);

    // 4. match + gated rmsnorm -> out_n in-place into cs
    match_norm_kernel<<<NROW, 192, 0, stream>>>(cs, qbuf, gate, wtab, gnw);

    // 5. readout GEMM + fused GLU v2 -> y
    gemm_readout_glu<<<dim3(128, 3, 12), 256, 0, stream>>>(
        cs, CS_LD, 128L, WT_RO, 128, 49152L, y, 128);

    // 6. out = y @ W_out
    gemm_kernel<false><<<dim3(128, 6), 256, 0, stream>>>(y, 2304, WT_OUT, 2304,
                                                         (float*)d_out, 768, 2304, 768);
}

// Round 10
// 411.846 us; speedup vs baseline: 1.1243x; 1.0009x over previous
//
#include <hip/hip_runtime.h>
#include <hip/hip_bf16.h>

typedef __hip_bfloat16 bf16;
typedef __attribute__((ext_vector_type(8))) short short8;
typedef __attribute__((ext_vector_type(4))) float floatx4;

#define L_SEQ 4096
#define B_SZ 4
#define NROW 16384          // B*L
#define NK 12
#define DIM_CONV 1548
#define Z_LD 1552           // z0 row stride: [0,768)=kv, [768,1536)=q, [1536,1548)=s
#define OUT_CPLX 1536
#define CS_LD 1552          // cs row stride: [0,768)=re, [768,1536)=im, [1536,1548)=pw
#define NCHUNK 128
#define CLEN 32

__device__ __forceinline__ float bf2f(bf16 v) { return __bfloat162float(v); }
__device__ __forceinline__ float s2f(short v) {
    unsigned u = ((unsigned)(unsigned short)v) << 16;
    return __builtin_bit_cast(float, u);
}
__device__ __forceinline__ short f2s(float x) {
    bf16 b = __float2bfloat16(x);
    return __builtin_bit_cast(short, b);
}
__device__ __forceinline__ float frcp(float x) { return __builtin_amdgcn_rcpf(x); }
__device__ __forceinline__ float fsigmoid(float x) { return frcp(1.0f + __expf(-x)); }
__device__ __forceinline__ float fsilu(float x) { return x * fsigmoid(x); }
__device__ __forceinline__ float fsoftplus(float x) {
    return fmaxf(x, 0.0f) + __logf(1.0f + __expf(-fabsf(x)));
}

// ---------------------------------------------------------------------------
// GEMM core v2 (128x128 tile, 64x64 wave tile, BK=64, XOR swizzle).
// 124 regs/wave (60 VGPR + 64 AGPR acc), 32 KB LDS -> up to 4 blocks/CU.
//
// GRID NOTE (r7 lesson): use grid (Mtiles, Ntiles) with mb = blockIdx.x.
// XCD = linear_bid % 8; with Mtiles = 128 (multiple of 8), XCD = mb % 8 —
// each XCD statically owns Mtiles/8 A-panels for ALL nb rounds (fits 4 MB
// L2). The r7 axis-swap scattered panel-sharing blocks across XCDs and
// blew FETCH up 52 -> 230 MB (private L2s duplicate panels 8x).
// ---------------------------------------------------------------------------
#define GEMM_CORE2(A_, lda_, Bt_, ldb_, Kd_)                                             \
    __shared__ __align__(16) short lds_a[128 * 64];                                      \
    __shared__ __align__(16) short lds_b[128 * 64];                                      \
    const int tid = threadIdx.x;                                                         \
    const int wave = tid >> 6;                                                           \
    const int lane = tid & 63;                                                           \
    const bf16* ga[4];                                                                   \
    const bf16* gb[4];                                                                   \
    short* la[4];                                                                        \
    short* lb[4];                                                                        \
    _Pragma("unroll") for (int s = 0; s < 4; s++) {                                      \
        int p = s * 256 + tid;                                                           \
        int row = p >> 3;                                                                \
        int k8 = (p & 7) ^ (row & 7);                                                    \
        ga[s] = A_ + (size_t)row * lda_ + k8 * 8;                                        \
        gb[s] = Bt_ + (size_t)row * ldb_ + k8 * 8;                                       \
        la[s] = lds_a + (size_t)(s * 256 + wave * 64) * 8;                               \
        lb[s] = lds_b + (size_t)(s * 256 + wave * 64) * 8;                               \
    }                                                                                    \
    floatx4 acc[4][4];                                                                   \
    _Pragma("unroll") for (int i = 0; i < 4; i++)                                        \
        _Pragma("unroll") for (int j = 0; j < 4; j++)                                    \
            acc[i][j] = (floatx4){0.f, 0.f, 0.f, 0.f};                                   \
    const int wm = (wave >> 1) * 64;                                                     \
    const int wn = (wave & 1) * 64;                                                      \
    const int lrow = lane & 15;                                                          \
    const int lk8 = lane >> 4;                                                           \
    for (int k0 = 0; k0 < Kd_; k0 += 64) {                                               \
        _Pragma("unroll") for (int s = 0; s < 4; s++) {                                  \
            __builtin_amdgcn_global_load_lds((const __attribute__((address_space(1))) void*)ga[s], \
                                             (__attribute__((address_space(3))) void*)la[s], 16, 0, 0); \
            __builtin_amdgcn_global_load_lds((const __attribute__((address_space(1))) void*)gb[s], \
                                             (__attribute__((address_space(3))) void*)lb[s], 16, 0, 0); \
            ga[s] += 64; gb[s] += 64;                                                    \
        }                                                                                \
        __syncthreads();                                                                 \
        _Pragma("unroll") for (int s2 = 0; s2 < 2; s2++) {                               \
            short8 af[4], bfv[4];                                                        \
            const int k8L = s2 * 4 + lk8;                                                \
            _Pragma("unroll") for (int i = 0; i < 4; i++) {                              \
                int m = wm + i * 16 + lrow;                                              \
                af[i] = *(const short8*)(lds_a + ((size_t)m * 8 + (k8L ^ (m & 7))) * 8); \
            }                                                                            \
            _Pragma("unroll") for (int j = 0; j < 4; j++) {                              \
                int n = wn + j * 16 + lrow;                                              \
                bfv[j] = *(const short8*)(lds_b + ((size_t)n * 8 + (k8L ^ (n & 7))) * 8); \
            }                                                                            \
            _Pragma("unroll") for (int i = 0; i < 4; i++)                                \
                _Pragma("unroll") for (int j = 0; j < 4; j++)                            \
                    acc[i][j] = __builtin_amdgcn_mfma_f32_16x16x32_bf16(af[i], bfv[j], acc[i][j], 0, 0, 0); \
        }                                                                                \
        __syncthreads();                                                                 \
    }

template <bool OUT_BF16>
__global__ __launch_bounds__(256, 4) void gemm_kernel(
    const bf16* __restrict__ A, int lda,
    const bf16* __restrict__ Bt, int ldb,
    void* __restrict__ Cv, int ldc, int Kd, int nmax)
{
    const bf16* Ab = A + (size_t)blockIdx.x * 128 * lda;
    const bf16* Bb = Bt + (size_t)blockIdx.y * 128 * ldb;
    GEMM_CORE2(Ab, lda, Bb, ldb, Kd)
    const int orow = blockIdx.x * 128 + wm + (lk8 << 2);
    const int ocol = blockIdx.y * 128 + wn + lrow;
    if (OUT_BF16) {
        bf16* C = (bf16*)Cv;
#pragma unroll
        for (int i = 0; i < 4; i++)
#pragma unroll
            for (int j = 0; j < 4; j++)
                if (ocol + j * 16 < nmax)
#pragma unroll
                    for (int r = 0; r < 4; r++)
                        C[(size_t)(orow + i * 16 + r) * ldc + (ocol + j * 16)] =
                            __float2bfloat16(acc[i][j][r]);
    } else {
        float* C = (float*)Cv;
#pragma unroll
        for (int i = 0; i < 4; i++)
#pragma unroll
            for (int j = 0; j < 4; j++)
                if (ocol + j * 16 < nmax)
#pragma unroll
                    for (int r = 0; r < 4; r++)
                        C[(size_t)(orow + i * 16 + r) * ldc + (ocol + j * 16)] = acc[i][j][r];
    }
}

// ---------------------------------------------------------------------------
// Readout GEMM + fused GLU, v2: WT_RO uses 16-col-block interleave so a
// thread's acc[i][2p]=val and acc[i][2p+1]=gate are in the SAME lane ->
// GLU with no shuffle and half the sigmoids. Output staged through LDS
// (XOR-swizzled, conflict-free) then written as coalesced short8 — global
// store instructions 32 -> 4 per thread. (r6: v1 was 64 us, MfmaUtil 12%,
// VALUBusy 42%; r8: v2 below the 61.6 us top-5 cutoff.)
// ---------------------------------------------------------------------------
__global__ __launch_bounds__(256, 3) void gemm_readout_glu(
    const bf16* __restrict__ A, int lda, long a_zoff,
    const bf16* __restrict__ Bt, int ldb, long b_zoff,
    bf16* __restrict__ Y, int Kd)
{
    const int z = blockIdx.z;
    const bf16* Ab = A + (long)z * a_zoff + (size_t)blockIdx.x * 128 * lda;
    const bf16* Bb = Bt + (long)z * b_zoff + (size_t)blockIdx.y * 128 * ldb;
    GEMM_CORE2(Ab, lda, Bb, ldb, Kd)
    // GLU into LDS stage (reuse lds_a; K-loop's trailing barrier covers reuse)
    const int colb = wn >> 1;
#pragma unroll
    for (int i = 0; i < 4; i++) {
        const int row0 = wm + i * 16 + (lk8 << 2);
#pragma unroll
        for (int p = 0; p < 2; p++) {
            const int col = colb + p * 16 + lrow;
#pragma unroll
            for (int r = 0; r < 4; r++) {
                const int row = row0 + r;
                float v = acc[i][2 * p][r];
                float g = acc[i][2 * p + 1][r];
                lds_a[row * 64 + (col ^ ((row & 12) << 2))] = f2s(v * fsigmoid(g));
            }
        }
    }
    __syncthreads();
    bf16* Yk = Y + (long)z * 192 + (size_t)blockIdx.x * 128 * 2304 + (size_t)blockIdx.y * 64;
#pragma unroll
    for (int ch = tid; ch < 1024; ch += 256) {
        const int row = ch >> 3;
        const int c8 = (ch & 7) * 8;
        *(short8*)(Yk + (size_t)row * 2304 + c8) =
            *(const short8*)(lds_a + row * 64 + (c8 ^ ((row & 12) << 2)));
    }
}

// ---------------------------------------------------------------------------
// prep_kernel: ONE launch for x->bf16 convert, w_int table, and all 7 weight
// transposes (fp32->bf16, tiled 32x32 via LDS). blockIdx.x range-dispatched.
// gmode: 0 = plain transpose row=c; 1/2 = W_readout 16-col-block interleave
// (val -> (c>>4)*32+(c&15), gate -> +16) matching gemm_readout_glu v2.
// ---------------------------------------------------------------------------
#define PREP_CONV_BLKS 6144
#define PREP_WINT_BLKS 3
#define PREP_T0 (PREP_CONV_BLKS + PREP_WINT_BLKS)   // 6147
#define PREP_TOTAL (PREP_T0 + 4632)                  // 10779

__global__ __launch_bounds__(256) void prep_kernel(
    const float* __restrict__ x, const float* __restrict__ w_int_raw,
    const float* __restrict__ W_in, const float* __restrict__ W_gate,
    const float* __restrict__ W_out, const float* __restrict__ W_readout,
    bf16* __restrict__ xb, float* __restrict__ wtab,
    bf16* __restrict__ WT_IN, bf16* __restrict__ WT_GATE,
    bf16* __restrict__ WT_OUT, bf16* __restrict__ WT_RO)
{
    __shared__ float tle[32][33];
    const int blk = blockIdx.x;
    const int tid = threadIdx.x;

    if (blk < PREP_CONV_BLKS) {
        long gid = ((long)blk * 256 + tid) * 8;
        float4 a = *(const float4*)(x + gid);
        float4 b = *(const float4*)(x + gid + 4);
        short8 o;
        o[0] = f2s(a.x); o[1] = f2s(a.y); o[2] = f2s(a.z); o[3] = f2s(a.w);
        o[4] = f2s(b.x); o[5] = f2s(b.y); o[6] = f2s(b.z); o[7] = f2s(b.w);
        *(short8*)(xb + gid) = o;
        return;
    }
    if (blk < PREP_T0) {
        int i = (blk - PREP_CONV_BLKS) * 256 + tid;
        if (i < 768) {
            float e = __expf(w_int_raw[i]);
            wtab[i] = e * frcp(e + 1e-6f);
        }
        return;
    }
    int t = blk - PREP_T0;
    const float* in; bf16* out;
    int ld_in, ld_out, R, C, gmode, nx;
    if (t < 576) {                       // W_in kv cols -> WT_IN rows 0..767
        in = W_in; out = WT_IN; ld_in = 1548; ld_out = 768;
        R = 768; C = 768; gmode = 0; nx = 24;
    } else if (t < 1152) {               // W_in q cols 780.. -> rows 768..1535
        t -= 576;
        in = W_in + 780; out = WT_IN + 768L * 768; ld_in = 1548; ld_out = 768;
        R = 768; C = 768; gmode = 0; nx = 24;
    } else if (t < 1176) {               // W_in s cols 768..779 -> rows 1536..1547
        t -= 1152;
        in = W_in + 768; out = WT_IN + 1536L * 768; ld_in = 1548; ld_out = 768;
        R = 768; C = 12; gmode = 0; nx = 1;
    } else if (t < 2328) {               // W_gate
        t -= 1176;
        in = W_gate; out = WT_GATE; ld_in = 1536; ld_out = 768;
        R = 768; C = 1536; gmode = 0; nx = 48;
    } else if (t < 4056) {               // W_out
        t -= 2328;
        in = W_out; out = WT_OUT; ld_in = 768; ld_out = 2304;
        R = 2304; C = 768; gmode = 0; nx = 24;
    } else if (t < 4344) {               // W_readout val half (16-blk interleave)
        t -= 4056;
        int k = t / 24; t %= 24;
        in = W_readout + (long)k * 49152; out = WT_RO + (long)k * 49152;
        ld_in = 384; ld_out = 128; R = 128; C = 192; gmode = 1; nx = 6;
    } else {                             // W_readout gate half
        t -= 4344;
        int k = t / 24; t %= 24;
        in = W_readout + (long)k * 49152 + 192; out = WT_RO + (long)k * 49152;
        ld_in = 384; ld_out = 128; R = 128; C = 192; gmode = 2; nx = 6;
    }
    int c0 = (t % nx) * 32, r0 = (t / nx) * 32;
    int tx = tid & 31, ty = tid >> 5;    // 32x8
#pragma unroll
    for (int i = 0; i < 32; i += 8) {
        int r = r0 + ty + i, c = c0 + tx;
        if (r < R && c < C) tle[ty + i][tx] = in[(size_t)r * ld_in + c];
    }
    __syncthreads();
#pragma unroll
    for (int i = 0; i < 32; i += 8) {
        int c = c0 + ty + i, r = r0 + tx;
        if (c < C && r < R) {
            int orow2 = (gmode == 0) ? c
                       : ((c & 15) + ((c >> 4) << 5) + ((gmode == 2) ? 16 : 0));
            out[(size_t)orow2 * ld_out + r] = __float2bfloat16(tle[tx][ty + i]);
        }
    }
}

// ---------------------------------------------------------------------------
// scan_terms (pw fused): one block per rest=(b,chunk).
// ---------------------------------------------------------------------------
__global__ __launch_bounds__(256) void scan_terms(
    const bf16* __restrict__ z0, const float* __restrict__ conv_w,
    const float* __restrict__ theta_raw, const float* __restrict__ pscale,
    const float* __restrict__ decay, const float* __restrict__ sscale,
    const float* __restrict__ sbias,
    bf16* __restrict__ cs, bf16* __restrict__ qbuf, float* __restrict__ sums)
{
    __shared__ float pwl[CLEN][NK];
    const int rest = blockIdx.x;              // b*128 + chunk
    const int chunk = rest & (NCHUNK - 1);
    const int b = rest >> 7;
    const int l0 = chunk * CLEN;
    const int tau = threadIdx.x;
    const bf16* zb = z0 + (size_t)b * L_SEQ * Z_LD;
    bf16* csb = cs + (size_t)b * L_SEQ * CS_LD;
    const size_t bL = (size_t)b * L_SEQ;
    float* srow = sums + (size_t)rest * 1552;

    if (tau < NK) {
        const int k = tau;
        const int zc = 1536 + k;
        const int wc = 768 + k;
        float w0 = conv_w[0 * DIM_CONV + wc], w1 = conv_w[1 * DIM_CONV + wc];
        float w2 = conv_w[2 * DIM_CONV + wc], w3 = conv_w[3 * DIM_CONV + wc];
        float ss = sscale[k], sb = sbias[k];
        float slope = fsoftplus(decay[k]);
        float h1 = (l0 >= 3) ? bf2f(zb[(size_t)(l0 - 3) * Z_LD + zc]) : 0.f;
        float h2 = (l0 >= 2) ? bf2f(zb[(size_t)(l0 - 2) * Z_LD + zc]) : 0.f;
        float h3 = (l0 >= 1) ? bf2f(zb[(size_t)(l0 - 1) * Z_LD + zc]) : 0.f;
        for (int i = 0; i < CLEN; i++) {
            int l = l0 + i;
            float cur = bf2f(zb[(size_t)l * Z_LD + zc]);
            float s = fsilu(w0 * h1 + w1 * h2 + w2 * h3 + w3 * cur);
            h1 = h2; h2 = h3; h3 = cur;
            float pw = fsoftplus(ss * s + sb) * __expf(-slope * (float)(L_SEQ - 1 - l));
            pwl[i][k] = fminf(fmaxf(pw, 1e-4f), 5000.0f);
        }
    }
    __syncthreads();
    if (tau >= 194) return;

    if (tau < 96) {
        const int cv0 = tau * 8;
        const int k = cv0 >> 6;
        float wt[4][8], th[8];
#pragma unroll
        for (int t = 0; t < 4; t++)
#pragma unroll
            for (int j = 0; j < 8; j++) wt[t][j] = conv_w[t * DIM_CONV + cv0 + j];
#pragma unroll
        for (int j = 0; j < 8; j++)
            th[j] = 0.001f + 2.999f * fsigmoid(theta_raw[cv0 + j]);
        const float ps = pscale[k];
        float h1[8], h2[8], h3[8];
#pragma unroll
        for (int j = 0; j < 8; j++) { h1[j] = 0.f; h2[j] = 0.f; h3[j] = 0.f; }
        if (l0 >= 1) {
            short8 v = *(const short8*)(zb + (size_t)(l0 - 1) * Z_LD + cv0);
#pragma unroll
            for (int j = 0; j < 8; j++) h3[j] = s2f(v[j]);
            short8 u = *(const short8*)(zb + (size_t)(l0 - 2) * Z_LD + cv0);
#pragma unroll
            for (int j = 0; j < 8; j++) h2[j] = s2f(u[j]);
            short8 w = *(const short8*)(zb + (size_t)(l0 - 3) * Z_LD + cv0);
#pragma unroll
            for (int j = 0; j < 8; j++) h1[j] = s2f(w[j]);
        }
        float sre[8], sim[8];
#pragma unroll
        for (int j = 0; j < 8; j++) { sre[j] = 0.f; sim[j] = 0.f; }
        for (int i = 0; i < CLEN; i++) {
            int l = l0 + i;
            short8 zv = *(const short8*)(zb + (size_t)l * Z_LD + cv0);
            float pw = pwl[i][k];
            short8 vr, vi;
#pragma unroll
            for (int j = 0; j < 8; j++) {
                float cur = s2f(zv[j]);
                float kv = fsilu(wt[0][j] * h1[j] + wt[1][j] * h2[j] + wt[2][j] * h3[j] + wt[3][j] * cur);
                h1[j] = h2[j]; h2[j] = h3[j]; h3[j] = cur;
                float ksv = kv * ps;
                float phi = ksv * frcp(1.0f + fabsf(ksv)) * th[j];
                float sn = __sinf(phi);
                float cn = __cosf(phi);
                float kvw = kv * pw;
                short tr = f2s(kvw * cn);
                short ti = f2s(kvw * sn);
                vr[j] = tr; vi[j] = ti;
                sre[j] += s2f(tr);
                sim[j] += s2f(ti);
            }
            *(short8*)(csb + (size_t)l * CS_LD + cv0) = vr;
            *(short8*)(csb + (size_t)l * CS_LD + 768 + cv0) = vi;
        }
#pragma unroll
        for (int j = 0; j < 8; j++) {
            srow[cv0 + j] = sre[j];
            srow[768 + cv0 + j] = sim[j];
        }
    } else if (tau < 192) {
        const int qc0 = (tau - 96) * 8;
        const int zc0 = 768 + qc0;
        const int wc0 = 780 + qc0;
        float wt[4][8];
#pragma unroll
        for (int t = 0; t < 4; t++)
#pragma unroll
            for (int j = 0; j < 8; j++) wt[t][j] = conv_w[t * DIM_CONV + wc0 + j];
        float h1[8], h2[8], h3[8];
#pragma unroll
        for (int j = 0; j < 8; j++) { h1[j] = 0.f; h2[j] = 0.f; h3[j] = 0.f; }
        if (l0 >= 1) {
            short8 v = *(const short8*)(zb + (size_t)(l0 - 1) * Z_LD + zc0);
#pragma unroll
            for (int j = 0; j < 8; j++) h3[j] = s2f(v[j]);
            short8 u = *(const short8*)(zb + (size_t)(l0 - 2) * Z_LD + zc0);
#pragma unroll
            for (int j = 0; j < 8; j++) h2[j] = s2f(u[j]);
            short8 w = *(const short8*)(zb + (size_t)(l0 - 3) * Z_LD + zc0);
#pragma unroll
            for (int j = 0; j < 8; j++) h1[j] = s2f(w[j]);
        }
        for (int i = 0; i < CLEN; i++) {
            int l = l0 + i;
            short8 zv = *(const short8*)(zb + (size_t)l * Z_LD + zc0);
            short8 o;
#pragma unroll
            for (int j = 0; j < 8; j++) {
                float cur = s2f(zv[j]);
                float q = fsilu(wt[0][j] * h1[j] + wt[1][j] * h2[j] + wt[2][j] * h3[j] + wt[3][j] * cur);
                h1[j] = h2[j]; h2[j] = h3[j]; h3[j] = cur;
                o[j] = f2s(q);
            }
            *(short8*)(qbuf + (bL + l) * 768 + qc0) = o;
        }
    } else {
        const int k0 = (tau == 192) ? 0 : 8;
        const int nv = (tau == 192) ? 8 : 4;
        float spw[8];
#pragma unroll
        for (int j = 0; j < 8; j++) spw[j] = 0.f;
        for (int i = 0; i < CLEN; i++) {
            int l = l0 + i;
            short8 o;
#pragma unroll
            for (int j = 0; j < 8; j++) {
                float v = (j < nv) ? pwl[i][k0 + j] : 0.0f;
                short t = f2s(v);
                o[j] = t;
                spw[j] += s2f(t);
            }
            *(short8*)(csb + (size_t)l * CS_LD + 1536 + k0) = o;
        }
#pragma unroll
        for (int j = 0; j < 8; j++) srow[1536 + k0 + j] = spw[j];
    }
}

// ---------------------------------------------------------------------------
// scan_mid v2: parallel LDS-tiled exclusive scan over NCHUNK chunks.
// ---------------------------------------------------------------------------
#define SMID_COLS 64
__global__ __launch_bounds__(256) void scan_mid(float* __restrict__ sums)
{
    __shared__ float tle[NCHUNK][SMID_COLS];   // 32 KB
    const int b = blockIdx.y;
    const int c0 = blockIdx.x * SMID_COLS;
    const int tc = threadIdx.x & 63;
    const int tr = threadIdx.x >> 6;           // 0..3
    const int c = c0 + tc;
    const bool valid = (c < 1552);
    if (valid) {
#pragma unroll
        for (int i = tr; i < NCHUNK; i += 4)
            tle[i][tc] = sums[((size_t)(b * NCHUNK + i)) * 1552 + c];
    }
    __syncthreads();
    if (threadIdx.x < 64 && valid) {
        float run = 0.f;
        for (int i = 0; i < NCHUNK; i++) {
            float v = tle[i][tc];
            tle[i][tc] = run;
            run += v;
        }
    }
    __syncthreads();
    if (valid) {
#pragma unroll
        for (int i = tr; i < NCHUNK; i += 4)
            sums[((size_t)(b * NCHUNK + i)) * 1552 + c] = tle[i][tc];
    }
}

// ---------------------------------------------------------------------------
// scan_match (r9): fused scan_inplace + match_norm.
// Phase A (threads 0..193): in-place bf16 cumsum of the block's 32 rows —
// identical to old scan_inplace. Idle threads 194..255 stage wtab/gnw to LDS.
// Phase B: one wave per row (8 rows/wave); lane ln does 3 of match_norm's
// 8-col groups (tau = ln + 64g); RMS reduce via shfl (no block barriers).
// cs rows are L1/L2-hot from phase A -> eliminates match_norm's cold 48 MB
// cs re-read and its separate 16384-block launch. Numerics bit-identical
// (phase B reads the same rounded bf16 phase A stored; same in-place
// read-then-write aliasing pattern the old match_norm used).
// NOTE: gate GEMM must run BEFORE this kernel now (z0 dead after scan_terms).
// ---------------------------------------------------------------------------
__global__ __launch_bounds__(256) void scan_match(
    bf16* __restrict__ cs, const float* __restrict__ sums,
    const bf16* __restrict__ qbuf, const bf16* __restrict__ gate,
    const float* __restrict__ wtab, const float* __restrict__ gnw)
{
    __shared__ float swtab[768];
    __shared__ float sgnw[1536];
    const int rest = blockIdx.x;
    const int chunk = rest & (NCHUNK - 1);
    const int b = rest >> 7;
    const int tau = threadIdx.x;
    const size_t row0 = (size_t)(b * L_SEQ + chunk * CLEN);

    if (tau < 194) {
        const int c0 = tau * 8;
        float run[8];
        const float* srow = sums + (size_t)rest * 1552;
#pragma unroll
        for (int j = 0; j < 8; j++) run[j] = srow[c0 + j];
        bf16* p = cs + row0 * CS_LD + c0;
        for (int i = 0; i < CLEN; i++) {
            short8 v = *(const short8*)p;
            short8 o;
#pragma unroll
            for (int j = 0; j < 8; j++) {
                run[j] += s2f(v[j]);
                o[j] = f2s(run[j]);
            }
            *(short8*)p = o;
            p += CS_LD;
        }
    } else {
        for (int i = tau - 194; i < 768; i += 62) swtab[i] = wtab[i];
        for (int i = tau - 194; i < 1536; i += 62) sgnw[i] = gnw[i];
    }
    __syncthreads();

    const int wv = tau >> 6;
    const int ln = tau & 63;
    for (int rr = 0; rr < 8; rr++) {
        const int r = wv * 8 + rr;
        bf16* csr = cs + (row0 + r) * CS_LD;
        const bf16* qr = qbuf + (row0 + r) * 768;
        const bf16* gr = gate + (row0 + r) * OUT_CPLX;
        float vals[3][8];
        float ss = 0.0f;
#pragma unroll
        for (int g = 0; g < 3; g++) {
            const int c0 = (ln + 64 * g) * 8;
            const int k = c0 >> 7;
            const int r0 = c0 & 127;
            const int h0 = r0 & 63;
            const bool is_im = (r0 >= 64);
            const int kq = k >> 1;
            const float idn = 1.0f / fmaxf(bf2f(csr[1536 + k]), 1e-4f);
            short8 re8 = *(const short8*)(csr + k * 64 + h0);
            short8 im8 = *(const short8*)(csr + 768 + k * 64 + h0);
            short8 qa = *(const short8*)(qr + kq * 128 + 2 * h0);
            short8 qb = *(const short8*)(qr + kq * 128 + 2 * h0 + 8);
            short8 g8 = *(const short8*)(gr + c0);
#pragma unroll
            for (int j = 0; j < 8; j++) {
                float sre = s2f(re8[j]) * idn;
                float sim = s2f(im8[j]) * idn;
                short qre_s = (j < 4) ? qa[2 * j] : qb[2 * (j - 4)];
                short qim_s = (j < 4) ? qa[2 * j + 1] : qb[2 * (j - 4) + 1];
                float qre = s2f(qre_s);
                float qim = s2f(qim_s);
                float m = is_im ? (sim * qre - sre * qim) : (sre * qre + sim * qim);
                m *= 0.125f * swtab[k * 64 + h0 + j];
                float hv = m * fsilu(s2f(g8[j]));
                vals[g][j] = hv;
                ss += hv * hv;
            }
        }
#pragma unroll
        for (int off = 32; off > 0; off >>= 1) ss += __shfl_down(ss, off);
        float total = __shfl(ss, 0);
        float inv_rms = rsqrtf(total * (1.0f / (float)OUT_CPLX) + 1e-6f);
#pragma unroll
        for (int g = 0; g < 3; g++) {
            const int c0 = (ln + 64 * g) * 8;
            short8 o;
#pragma unroll
            for (int j = 0; j < 8; j++) o[j] = f2s(vals[g][j] * inv_rms * sgnw[c0 + j]);
            *(short8*)(csr + c0) = o;
        }
    }
}

__global__ void sentinel_kernel(float* out, float v)
{
    if (threadIdx.x == 0) out[0] = v;
}

// ---------------------------------------------------------------------------
// Workspace layout (bytes)
// ---------------------------------------------------------------------------
#define XB_OFF 0UL                 // 16384x768 bf16       25,165,824
#define WT_IN_OFF 25165824UL       // 1792x768 bf16         2,752,512 (rows 1548+ unwritten, clipped)
#define WT_GATE_OFF 27918336UL     // 1536x768 bf16         2,359,296
#define WT_OUT_OFF 30277632UL      // 768x2304 bf16         3,538,944
#define WT_RO_OFF 33816576UL       // 12x384x128 bf16       1,179,648
#define SUMS_OFF 34996224UL        // 512x1552 fp32         3,178,496
#define WTAB_OFF 38174720UL        // 768 fp32                  3,072
#define CS_OFF 38177792UL          // 16384x1552 bf16      50,855,936
#define A_OFF 89033728UL           // z0 16384x1552 bf16; later gate; later y (75,497,472)
#define QBUF_OFF 139889664UL       // 16384x768 bf16       25,165,824 (overlapped by y tail later)
#define WS_NEEDED 165055488UL      // < 166,932,480 proven available

extern "C" void kernel_launch(void* const* d_in, const int* in_sizes, int n_in,
                              void* d_out, int out_size, void* d_ws, size_t ws_size,
                              hipStream_t stream)
{
    const float* x = (const float*)d_in[0];
    const float* W_in = (const float*)d_in[1];
    const float* conv_w = (const float*)d_in[2];
    const float* theta_raw = (const float*)d_in[3];
    const float* w_int_raw = (const float*)d_in[4];
    const float* decay_slopes = (const float*)d_in[5];
    const float* score_scale = (const float*)d_in[6];
    const float* score_bias = (const float*)d_in[7];
    const float* phase_scale = (const float*)d_in[8];
    const float* gnw = (const float*)d_in[9];
    const float* W_readout = (const float*)d_in[10];
    const float* W_gate = (const float*)d_in[11];
    const float* W_out = (const float*)d_in[12];

    if (ws_size < WS_NEEDED) {
        sentinel_kernel<<<1, 64, 0, stream>>>((float*)d_out, (float)ws_size);
        return;
    }

    char* ws = (char*)d_ws;
    bf16* xb = (bf16*)(ws + XB_OFF);
    bf16* WT_IN = (bf16*)(ws + WT_IN_OFF);
    bf16* WT_GATE = (bf16*)(ws + WT_GATE_OFF);
    bf16* WT_OUT = (bf16*)(ws + WT_OUT_OFF);
    bf16* WT_RO = (bf16*)(ws + WT_RO_OFF);
    float* sums = (float*)(ws + SUMS_OFF);
    float* wtab = (float*)(ws + WTAB_OFF);
    bf16* cs = (bf16*)(ws + CS_OFF);
    bf16* z0 = (bf16*)(ws + A_OFF);
    bf16* gate = (bf16*)(ws + A_OFF);
    bf16* y = (bf16*)(ws + A_OFF);
    bf16* qbuf = (bf16*)(ws + QBUF_OFF);

    // 0. single prep launch: convert x, wint table, all weight transposes
    prep_kernel<<<PREP_TOTAL, 256, 0, stream>>>(
        x, w_int_raw, W_in, W_gate, W_out, W_readout,
        xb, wtab, WT_IN, WT_GATE, WT_OUT, WT_RO);

    // 1. z0 = x @ W_in (grid (128, N): XCD = mb%8 -> per-XCD A-panel affinity)
    gemm_kernel<true><<<dim3(128, 13), 256, 0, stream>>>(xb, 768, WT_IN, 768,
                                                         z0, Z_LD, 768, 1548);

    // 2. terms (pw fused in-block) + chunk sums; parallel chunk scan
    scan_terms<<<512, 256, 0, stream>>>(z0, conv_w, theta_raw, phase_scale,
                                        decay_slopes, score_scale, score_bias,
                                        cs, qbuf, sums);
    scan_mid<<<dim3(25, 4), 256, 0, stream>>>(sums);

    // 3. gate = x @ W_gate (overwrites z0 — z0 dead after scan_terms)
    gemm_kernel<true><<<dim3(128, 12), 256, 0, stream>>>(xb, 768, WT_GATE, 768,
                                                         gate, 1536, 768, 1536);

    // 4. fused cumsum + match + gated rmsnorm -> out_n in-place into cs
    scan_match<<<512, 256, 0, stream>>>(cs, sums, qbuf, gate, wtab, gnw);

    // 5. readout GEMM + fused GLU v2 -> y
    gemm_readout_glu<<<dim3(128, 3, 12), 256, 0, stream>>>(
        cs, CS_LD, 128L, WT_RO, 128, 49152L, y, 128);

    // 6. out = y @ W_out
    gemm_kernel<false><<<dim3(128, 6), 256, 0, stream>>>(y, 2304, WT_OUT, 2304,
                                                         (float*)d_out, 768, 2304, 768);
}